// Round 5
// baseline (106.597 us; speedup 1.0000x reference)
//
#include <hip/hip_runtime.h>
#include <math.h>

// LogPolar resample: data (32,3,512,512) f32 -> out (32,3,512,512) f32.
//
// R5 structure:
//  1) table_kernel (2 blocks): rad=exp(j*max_r/512) (j-only), cos/sin(ang(i))
//     (i-only) -> 3*512 floats in d_ws. Correctly-rounded f32 via f64 libm,
//     bit-identical to the chain validated in R2-R4 (discontinuous trunc/mask
//     decisions must match the np reference exactly).
//  2) resample_kernel (16384 blocks): rebuilds X,Y from tables with native
//     f32 ops (__fmul_rn/__fadd_rn == "exact op, round once" -> bit-identical
//     to R2). f64 weights unchanged.
//     GATHER PATH (new): per corner ROW, one aligned float4 load at x&~3
//     covers both x and x+1 for x%4 in {0,1,2}; x%4==3 lanes take an
//     exec-masked scalar fallback. Cuts gather line-requests ~19M -> ~11M
//     (R4 post-mortem: at 101us we sat at ~0.77 req/cyc/CU = the TA request
//     wall; HBM 24%, VALU 5%, occ 42% -> nothing else was the limiter).
//     PPB=6, NG=16, blockIdx&7 = XCD plane partition; nt stores.

#define HW (512 * 512)
#define NPIX (512 * 512)
#define PLANES 96
#define PPB 6   // planes per resample block
#define NG 16   // plane groups (PLANES/PPB)

// ---------------- table kernel: 512 entries of rad/cos/sin ----------------
__global__ __launch_bounds__(256) void table_kernel(float* __restrict__ radT,
                                                    float* __restrict__ cT,
                                                    float* __restrict__ sT) {
  const int t = blockIdx.x * 256 + threadIdx.x;  // 0..511

  // max_r = log(sqrt(512^2+512^2)/2 * 700), all in f32 steps (CR via f64)
  const float sq_f = (float)sqrt(524288.0);             // f32 sqrt (CR)
  const float half_f = sq_f * 0.5f;                     // exact
  const float prod_f = (float)((double)half_f * 700.0); // f32 mul emulated
  const float maxr_f = (float)log((double)prod_f);      // f32 log (CR)

  // rad = exp(t * max_r / 512) in f32 steps
  const float t1 = (float)((double)(float)t * (double)maxr_f); // f32 mul
  const float tt = t1 * (1.0f / 512.0f);                       // exact (pow2)
  radT[t] = (float)exp((double)tt);                            // f32 exp (CR)

  // ang = t * 2.0 * f32(pi) / 512 in f32 steps
  const float two_i = (float)(2 * t);  // exact
  const float ang1 = (float)((double)two_i * (double)(float)M_PI); // f32 mul
  const float ang = ang1 * (1.0f / 512.0f);                        // exact
  cT[t] = (float)cos((double)ang);  // f32 cos (CR)
  sT[t] = (float)sin((double)ang);  // f32 sin (CR)
}

// ---------------- resample kernel ----------------
__global__ __launch_bounds__(256) void resample_kernel(
    const float* __restrict__ in, float* __restrict__ out,
    const float* __restrict__ radT, const float* __restrict__ cT,
    const float* __restrict__ sT) {
  const int g = blockIdx.x & (NG - 1);   // plane group; g&7 = XCD
  const int pixblock = blockIdx.x >> 4;  // 0..1023
  const int pix = pixblock * 256 + (int)threadIdx.x;
  const int i = pix >> 9;   // theta bin (block-uniform)
  const int j = pix & 511;  // radius bin

  const float rad = radT[j];
  const float c = cT[i];
  const float s = sT[i];

  // Native f32 ops == "exact in f64, round once" -> X,Y bit-identical to the
  // validated R2 chain.
  const float X = __fadd_rn(256.0f, __fmul_rn(rad, c));
  const float Y = __fsub_rn(256.0f, __fmul_rn(rad, s));

  const int p0 = g * PPB;
  float* op = out + (size_t)p0 * HW + pix;

  const bool inb = (X >= 0.0f) && (X < 512.0f) && (Y >= 0.0f) && (Y < 512.0f);
  if (!inb) {
#pragma unroll
    for (int p = 0; p < PPB; ++p) {
      __builtin_nontemporal_store(0.0f, op);
      op += HW;
    }
    return;
  }

  // corner indices + f64 weights (bit-identical to R2)
  const int yd = (int)Y;  // trunc == floor for Y in [0,512)
  const int xd = (int)X;
  const int yu = min(yd + 1, 511);
  const int xu = min(xd + 1, 511);
  const double Xd = (double)X, Yd = (double)Y;
  const double dyd = (Yd - (double)yd) * (Yd - (double)yd);
  const double dyu = (Yd - (double)yu) * (Yd - (double)yu);
  const double dxd = (Xd - (double)xd) * (Xd - (double)xd);
  const double dxu = (Xd - (double)xu) * (Xd - (double)xu);
  const double dd = dyd + dxd;
  const double du = dyd + dxu;
  const double ud = dyu + dxd;
  const double uu = dyu + dxu;
  const double inv = 1.0 / (dd + du + ud + uu);
  const float wdd = (float)(dd * inv);
  const float wdu = (float)(du * inv);
  const float wud = (float)(ud * inv);
  const float wuu = (float)(uu * inv);

  // merged row-pair gather: one aligned float4 per corner row covers
  // (x, x+1) for q = xd%4 in {0,1,2}; q==3 lanes take exec-masked fallback.
  const int q = xd & 3;
  const int rowd4 = yd * 512 + (xd & ~3);  // 16B-aligned element offset
  const int rowu4 = yu * 512 + (xd & ~3);
  const int id01 = yd * 512 + xu;  // fallback addresses (always valid)
  const int iu01 = yu * 512 + xu;

  const float* ip = in + (size_t)p0 * HW;
#pragma unroll
  for (int p = 0; p < PPB; ++p) {
    const float4 vd = *(const float4*)(ip + rowd4);
    const float4 vu = *(const float4*)(ip + rowu4);
    const float a00 = (q == 0) ? vd.x : (q == 1) ? vd.y : (q == 2) ? vd.z : vd.w;
    const float a10 = (q == 0) ? vu.x : (q == 1) ? vu.y : (q == 2) ? vu.z : vu.w;
    float a01, a11;
    if (q == 3) {            // exec-masked: ~25% of lanes
      a01 = ip[id01];
      a11 = ip[iu01];
    } else {
      a01 = (q == 0) ? vd.y : (q == 1) ? vd.z : vd.w;
      a11 = (q == 0) ? vu.y : (q == 1) ? vu.z : vu.w;
    }
    const float v = wdd * a00 + wdu * a01 + wud * a10 + wuu * a11;
    __builtin_nontemporal_store(v, op);
    ip += HW;
    op += HW;
  }
}

// ---------------- fallback: proven R2 monolithic kernel ----------------
__global__ __launch_bounds__(256) void logpolar_mono(
    const float* __restrict__ in, float* __restrict__ out) {
  const int pix = blockIdx.x * 256 + threadIdx.x;
  const int i = pix >> 9;
  const int j = pix & 511;

  const float sq_f = (float)sqrt(524288.0);
  const float half_f = sq_f * 0.5f;
  const float prod_f = (float)((double)half_f * 700.0);
  const float maxr_f = (float)log((double)prod_f);
  const float t1 = (float)((double)(float)j * (double)maxr_f);
  const float t = t1 * (1.0f / 512.0f);
  const float rad_f = (float)exp((double)t);
  const float two_i = (float)(2 * i);
  const float ang1 = (float)((double)two_i * (double)(float)M_PI);
  const float ang = ang1 * (1.0f / 512.0f);
  const float c_f = (float)cos((double)ang);
  const float s_f = (float)sin((double)ang);
  const float X0 = (float)((double)rad_f * (double)c_f);
  const float Y0 = (float)((double)rad_f * (double)s_f);
  const float X = (float)(256.0 + (double)X0);
  const float Y = (float)(256.0 - (double)Y0);

  const bool inb = (X >= 0.0f) && (X < 512.0f) && (Y >= 0.0f) && (Y < 512.0f);

  float wdd = 0.f, wdu = 0.f, wud = 0.f, wuu = 0.f;
  int idd = 0, idu = 0, iud = 0, iuu = 0;
  if (inb) {
    const int yd = (int)Y;
    const int xd = (int)X;
    const int yu = min(yd + 1, 511);
    const int xu = min(xd + 1, 511);
    const double Xd = (double)X, Yd = (double)Y;
    const double dyd = (Yd - (double)yd) * (Yd - (double)yd);
    const double dyu = (Yd - (double)yu) * (Yd - (double)yu);
    const double dxd = (Xd - (double)xd) * (Xd - (double)xd);
    const double dxu = (Xd - (double)xu) * (Xd - (double)xu);
    const double dd = dyd + dxd;
    const double du = dyd + dxu;
    const double ud = dyu + dxd;
    const double uu = dyu + dxu;
    const double inv = 1.0 / (dd + du + ud + uu);
    wdd = (float)(dd * inv);
    wdu = (float)(du * inv);
    wud = (float)(ud * inv);
    wuu = (float)(uu * inv);
    idd = yd * 512 + xd;
    idu = yd * 512 + xu;
    iud = yu * 512 + xd;
    iuu = yu * 512 + xu;
  }

  const float* __restrict__ ip = in;
  float* __restrict__ op = out + pix;
#pragma unroll 4
  for (int p = 0; p < PLANES; ++p) {
    float v = 0.0f;
    if (inb) {
      v = wdd * ip[idd] + wdu * ip[idu] + wud * ip[iud] + wuu * ip[iuu];
    }
    *op = v;
    ip += HW;
    op += HW;
  }
}

extern "C" void kernel_launch(void* const* d_in, const int* in_sizes, int n_in,
                              void* d_out, int out_size, void* d_ws,
                              size_t ws_size, hipStream_t stream) {
  const float* in = (const float*)d_in[0];
  float* out = (float*)d_out;

  const size_t table_bytes = 3 * 512 * sizeof(float);  // 6 KB
  if (ws_size >= table_bytes) {
    float* radT = (float*)d_ws;
    float* cT = radT + 512;
    float* sT = cT + 512;
    table_kernel<<<dim3(2), dim3(256), 0, stream>>>(radT, cT, sT);
    resample_kernel<<<dim3((NPIX / 256) * NG), dim3(256), 0, stream>>>(
        in, out, radT, cT, sT);
  } else {
    logpolar_mono<<<dim3(NPIX / 256), dim3(256), 0, stream>>>(in, out);
  }
}

// Round 6
// 62.893 us; speedup vs baseline: 1.6949x; 1.6949x over previous
//
#include <hip/hip_runtime.h>
#include <math.h>

// LogPolar resample: data (32,3,512,512) f32 -> out (32,3,512,512) f32.
//
// R6 structure:
//  1) table_kernel (2 blocks): rad=exp(j*max_r/512) (j-only), cos/sin(ang(i))
//     (i-only) -> 3*512 floats in d_ws. Correctly-rounded f32 via f64 libm,
//     bit-identical to the chain validated in R2-R5.
//  2) resample_kernel (32768 blocks = 131k waves): rebuilds X,Y from tables
//     with native f32 ops (__fmul_rn/__fadd_rn == "exact op, round once" ->
//     X,Y and thus ALL discontinuous trunc/mask decisions bit-identical to
//     the validated chain). Weights in f32 now (error ~1e-7 << 0.065 thr;
//     only X,Y need exactness). PPB=3, NG=32; blocks with (blockIdx&7)=k have
//     groups {k,k+8,k+16,k+24} -> 12 planes per XCD L2, same as R4/R5.
//     Scalar gathers (R5's float4 merge REGRESSED: halved instructions but
//     doubled L1 return bytes -> request count is not the binding constraint;
//     latency hiding is — so we double wave count instead).

#define HW (512 * 512)
#define NPIX (512 * 512)
#define PLANES 96
#define PPB 3   // planes per resample block
#define NG 32   // plane groups (PLANES/PPB)

// ---------------- table kernel: 512 entries of rad/cos/sin ----------------
__global__ __launch_bounds__(256) void table_kernel(float* __restrict__ radT,
                                                    float* __restrict__ cT,
                                                    float* __restrict__ sT) {
  const int t = blockIdx.x * 256 + threadIdx.x;  // 0..511

  // max_r = log(sqrt(512^2+512^2)/2 * 700), all in f32 steps (CR via f64)
  const float sq_f = (float)sqrt(524288.0);             // f32 sqrt (CR)
  const float half_f = sq_f * 0.5f;                     // exact
  const float prod_f = (float)((double)half_f * 700.0); // f32 mul emulated
  const float maxr_f = (float)log((double)prod_f);      // f32 log (CR)

  // rad = exp(t * max_r / 512) in f32 steps
  const float t1 = (float)((double)(float)t * (double)maxr_f); // f32 mul
  const float tt = t1 * (1.0f / 512.0f);                       // exact (pow2)
  radT[t] = (float)exp((double)tt);                            // f32 exp (CR)

  // ang = t * 2.0 * f32(pi) / 512 in f32 steps
  const float two_i = (float)(2 * t);  // exact
  const float ang1 = (float)((double)two_i * (double)(float)M_PI); // f32 mul
  const float ang = ang1 * (1.0f / 512.0f);                        // exact
  cT[t] = (float)cos((double)ang);  // f32 cos (CR)
  sT[t] = (float)sin((double)ang);  // f32 sin (CR)
}

// ---------------- resample kernel ----------------
__global__ __launch_bounds__(256) void resample_kernel(
    const float* __restrict__ in, float* __restrict__ out,
    const float* __restrict__ radT, const float* __restrict__ cT,
    const float* __restrict__ sT) {
  const int g = blockIdx.x & (NG - 1);   // plane group; g&7 = XCD partition
  const int pixblock = blockIdx.x >> 5;  // 0..1023
  const int pix = pixblock * 256 + (int)threadIdx.x;
  const int i = pix >> 9;   // theta bin (block-uniform)
  const int j = pix & 511;  // radius bin

  const float rad = radT[j];
  const float c = cT[i];
  const float s = sT[i];

  // Native f32 ops == "exact in f64, round once" -> X,Y bit-identical to the
  // validated chain; all trunc/mask decisions follow from X,Y alone.
  const float X = __fadd_rn(256.0f, __fmul_rn(rad, c));
  const float Y = __fsub_rn(256.0f, __fmul_rn(rad, s));

  const int p0 = g * PPB;
  float* op = out + (size_t)p0 * HW + pix;

  const bool inb = (X >= 0.0f) && (X < 512.0f) && (Y >= 0.0f) && (Y < 512.0f);
  if (!inb) {
#pragma unroll
    for (int p = 0; p < PPB; ++p) {
      __builtin_nontemporal_store(0.0f, op);
      op += HW;
    }
    return;
  }

  // corner indices (decisions from bit-exact X,Y) + f32 weights
  // (weight rounding ~1e-7 * |data|, threshold is 6.5e-2 -> safe)
  const int yd = (int)Y;  // trunc == floor for Y in [0,512)
  const int xd = (int)X;
  const int yu = min(yd + 1, 511);
  const int xu = min(xd + 1, 511);
  const float fyd = (Y - (float)yd) * (Y - (float)yd);
  const float fyu = (Y - (float)yu) * (Y - (float)yu);
  const float fxd = (X - (float)xd) * (X - (float)xd);
  const float fxu = (X - (float)xu) * (X - (float)xu);
  const float dd = fyd + fxd;
  const float du = fyd + fxu;
  const float ud = fyu + fxd;
  const float uu = fyu + fxu;
  const float inv = 1.0f / (dd + du + ud + uu);
  const float wdd = dd * inv;
  const float wdu = du * inv;
  const float wud = ud * inv;
  const float wuu = uu * inv;

  const int i00 = yd * 512 + xd;
  const int i01 = yd * 512 + xu;
  const int i10 = yu * 512 + xd;
  const int i11 = yu * 512 + xu;

  const float* ip = in + (size_t)p0 * HW;
#pragma unroll
  for (int p = 0; p < PPB; ++p) {
    const float v =
        wdd * ip[i00] + wdu * ip[i01] + wud * ip[i10] + wuu * ip[i11];
    __builtin_nontemporal_store(v, op);
    ip += HW;
    op += HW;
  }
}

// ---------------- fallback: proven R2 monolithic kernel ----------------
__global__ __launch_bounds__(256) void logpolar_mono(
    const float* __restrict__ in, float* __restrict__ out) {
  const int pix = blockIdx.x * 256 + threadIdx.x;
  const int i = pix >> 9;
  const int j = pix & 511;

  const float sq_f = (float)sqrt(524288.0);
  const float half_f = sq_f * 0.5f;
  const float prod_f = (float)((double)half_f * 700.0);
  const float maxr_f = (float)log((double)prod_f);
  const float t1 = (float)((double)(float)j * (double)maxr_f);
  const float t = t1 * (1.0f / 512.0f);
  const float rad_f = (float)exp((double)t);
  const float two_i = (float)(2 * i);
  const float ang1 = (float)((double)two_i * (double)(float)M_PI);
  const float ang = ang1 * (1.0f / 512.0f);
  const float c_f = (float)cos((double)ang);
  const float s_f = (float)sin((double)ang);
  const float X0 = (float)((double)rad_f * (double)c_f);
  const float Y0 = (float)((double)rad_f * (double)s_f);
  const float X = (float)(256.0 + (double)X0);
  const float Y = (float)(256.0 - (double)Y0);

  const bool inb = (X >= 0.0f) && (X < 512.0f) && (Y >= 0.0f) && (Y < 512.0f);

  float wdd = 0.f, wdu = 0.f, wud = 0.f, wuu = 0.f;
  int idd = 0, idu = 0, iud = 0, iuu = 0;
  if (inb) {
    const int yd = (int)Y;
    const int xd = (int)X;
    const int yu = min(yd + 1, 511);
    const int xu = min(xd + 1, 511);
    const double Xd = (double)X, Yd = (double)Y;
    const double dyd = (Yd - (double)yd) * (Yd - (double)yd);
    const double dyu = (Yd - (double)yu) * (Yd - (double)yu);
    const double dxd = (Xd - (double)xd) * (Xd - (double)xd);
    const double dxu = (Xd - (double)xu) * (Xd - (double)xu);
    const double dd = dyd + dxd;
    const double du = dyd + dxu;
    const double ud = dyu + dxd;
    const double uu = dyu + dxu;
    const double inv = 1.0 / (dd + du + ud + uu);
    wdd = (float)(dd * inv);
    wdu = (float)(du * inv);
    wud = (float)(ud * inv);
    wuu = (float)(uu * inv);
    idd = yd * 512 + xd;
    idu = yd * 512 + xu;
    iud = yu * 512 + xd;
    iuu = yu * 512 + xu;
  }

  const float* __restrict__ ip = in;
  float* __restrict__ op = out + pix;
#pragma unroll 4
  for (int p = 0; p < PLANES; ++p) {
    float v = 0.0f;
    if (inb) {
      v = wdd * ip[idd] + wdu * ip[idu] + wud * ip[iud] + wuu * ip[iuu];
    }
    *op = v;
    ip += HW;
    op += HW;
  }
}

extern "C" void kernel_launch(void* const* d_in, const int* in_sizes, int n_in,
                              void* d_out, int out_size, void* d_ws,
                              size_t ws_size, hipStream_t stream) {
  const float* in = (const float*)d_in[0];
  float* out = (float*)d_out;

  const size_t table_bytes = 3 * 512 * sizeof(float);  // 6 KB
  if (ws_size >= table_bytes) {
    float* radT = (float*)d_ws;
    float* cT = radT + 512;
    float* sT = cT + 512;
    table_kernel<<<dim3(2), dim3(256), 0, stream>>>(radT, cT, sT);
    resample_kernel<<<dim3((NPIX / 256) * NG), dim3(256), 0, stream>>>(
        in, out, radT, cT, sT);
  } else {
    logpolar_mono<<<dim3(NPIX / 256), dim3(256), 0, stream>>>(in, out);
  }
}